// Round 4
// baseline (256.920 us; speedup 1.0000x reference)
//
#include <hip/hip_runtime.h>
#include <cstdint>
#include <cstddef>

typedef __attribute__((ext_vector_type(8))) short short8;
typedef __attribute__((ext_vector_type(4))) float f32x4;
typedef unsigned int u32;

#define MFMA_BF16(a, b, c) __builtin_amdgcn_mfma_f32_16x16x32_bf16((a), (b), (c), 0, 0, 0)

// ---------------------------------------------------------------------------
// helpers
// ---------------------------------------------------------------------------
__device__ __forceinline__ void async16(const void* g, void* l) {
  __builtin_amdgcn_global_load_lds(
      (const __attribute__((address_space(1))) u32*)g,
      (__attribute__((address_space(3))) u32*)l, 16, 0, 0);
}

__device__ __forceinline__ short f2bf(float f) {
  u32 u = __builtin_bit_cast(u32, f);
  u += 0x7fffu + ((u >> 16) & 1u);  // round-to-nearest-even
  return (short)(u >> 16);
}

// truncating pack: [bf16(lo) | bf16(hi)<<16] in ONE v_perm_b32
__device__ __forceinline__ u32 pack_bf16_trunc(float lo, float hi) {
  return __builtin_amdgcn_perm(__builtin_bit_cast(u32, hi),
                               __builtin_bit_cast(u32, lo), 0x07060302u);
}

// ---------------------------------------------------------------------------
// fused cast fp32 -> bf16 for x, w_attn (q-rows pre-scaled), w_proj
// region sizes (float4 units): x 2097152, wa 786432 (first 262144 scaled), wp 262144
// ---------------------------------------------------------------------------
__global__ __launch_bounds__(256) void cast_all_kernel(
    const float* __restrict__ x, const float* __restrict__ wa,
    const float* __restrict__ wp, short* __restrict__ xb,
    short* __restrict__ wab, short* __restrict__ wpb) {
  const int i = blockIdx.x * blockDim.x + threadIdx.x;
  const float4* src;
  short4* dst;
  float sc = 1.0f;
  if (i < 2097152) {
    src = (const float4*)x + i;
    dst = (short4*)xb + i;
  } else if (i < 2883584) {
    const int j = i - 2097152;
    if (j < 262144) sc = 0.18033688011112042f;  // 1/sqrt(64)*log2(e)
    src = (const float4*)wa + j;
    dst = (short4*)wab + j;
  } else {
    const int j = i - 2883584;
    src = (const float4*)wp + j;
    dst = (short4*)wpb + j;
  }
  float4 v = *src;
  short4 r;
  r.x = f2bf(v.x * sc); r.y = f2bf(v.y * sc);
  r.z = f2bf(v.z * sc); r.w = f2bf(v.w * sc);
  *dst = r;
}

// ---------------------------------------------------------------------------
// C[M][N] = A[M][K] * Bt[N][K]^T   (bf16-as-short in, fp32 accumulate)
// BK=64 — 32 MFMAs + 16 ds_reads per barrier. 128x128 tile,
// single-buffered 32 KB LDS. XCD swizzle (needs gridDim.y==64).
// LDS: 128 B rows, XOR-chunk placement: slot s holds
// T[row=s>>3][chunk=(s&7)^(row&7)]; frag reads at chunk (kk*4+quad)^(l15&7)
// = 2-way bank alias = free (m136).
// ---------------------------------------------------------------------------
template <bool OUT_BF16>
__global__ __launch_bounds__(256) void gemm_bt_kernel(
    const short* __restrict__ A, const short* __restrict__ Bt,
    void* __restrict__ Cv, int M, int N, int K) {
  __shared__ __align__(16) short As[128 * 64];
  __shared__ __align__(16) short Bs[128 * 64];

  const int tid  = threadIdx.x;
  const int lane = tid & 63;
  const int wave = tid >> 6;
  const int quad = lane >> 4;
  const int l15  = lane & 15;

  // XCD swizzle (gridDim.y == 64): linear id -> (bx, by)
  const int id  = blockIdx.y * gridDim.x + blockIdx.x;
  const int xcd = id & 7;
  const int j   = id >> 3;
  const int by  = xcd * 8 + (j & 7);
  const int bx  = j >> 3;
  const int bm  = by * 128;
  const int bn  = bx * 128;

  const int wm = (wave >> 1) * 64;
  const int wn = (wave & 1) * 64;

  f32x4 acc[4][4];
#pragma unroll
  for (int i = 0; i < 4; ++i)
#pragma unroll
    for (int jj = 0; jj < 4; ++jj) acc[i][jj] = (f32x4){0.f, 0.f, 0.f, 0.f};

  // staging: 128 rows x 128 B = 1024 slots/tile, 4 slots/thread/tile.
  int srow[4], scol[4];
#pragma unroll
  for (int it = 0; it < 4; ++it) {
    const int s = tid + it * 256;
    srow[it] = s >> 3;
    scol[it] = ((s & 7) ^ (srow[it] & 7)) * 8;
  }
  const int xk = l15 & 7;  // frag-read chunk XOR

  for (int k0 = 0; k0 < K; k0 += 64) {
    __syncthreads();
#pragma unroll
    for (int it = 0; it < 4; ++it) {
      const int s = tid + it * 256;
      async16(A  + (size_t)(bm + srow[it]) * K + k0 + scol[it], &As[s * 8]);
      async16(Bt + (size_t)(bn + srow[it]) * K + k0 + scol[it], &Bs[s * 8]);
    }
    __syncthreads();

    short8 af[4][2], bf[4][2];
#pragma unroll
    for (int mt = 0; mt < 4; ++mt) {
      const int ra = (wm + mt * 16 + l15) * 64;
      af[mt][0] = *(const short8*)&As[ra + ((quad) ^ xk) * 8];
      af[mt][1] = *(const short8*)&As[ra + ((4 + quad) ^ xk) * 8];
    }
#pragma unroll
    for (int nt = 0; nt < 4; ++nt) {
      const int rb = (wn + nt * 16 + l15) * 64;
      bf[nt][0] = *(const short8*)&Bs[rb + ((quad) ^ xk) * 8];
      bf[nt][1] = *(const short8*)&Bs[rb + ((4 + quad) ^ xk) * 8];
    }
#pragma unroll
    for (int kk = 0; kk < 2; ++kk)
#pragma unroll
      for (int mt = 0; mt < 4; ++mt)
#pragma unroll
        for (int nt = 0; nt < 4; ++nt)
          acc[mt][nt] = MFMA_BF16(af[mt][kk], bf[nt][kk], acc[mt][nt]);
  }

  // epilogue: C/D layout col = lane&15, row = quad*4 + reg
#pragma unroll
  for (int mt = 0; mt < 4; ++mt) {
    const int r0e = bm + wm + mt * 16 + quad * 4;
#pragma unroll
    for (int nt = 0; nt < 4; ++nt) {
      const int c = bn + wn + nt * 16 + l15;
#pragma unroll
      for (int reg = 0; reg < 4; ++reg) {
        float v = acc[mt][nt][reg];
        if (OUT_BF16)
          ((short*)Cv)[(size_t)(r0e + reg) * N + c] = f2bf(v);
        else
          ((float*)Cv)[(size_t)(r0e + reg) * N + c] = v;
      }
    }
  }
}

// ---------------------------------------------------------------------------
// V transpose+repack: qkv v-part [B*T][h*64+d] -> fragment-major vt2:
//   vt2[((bh*32 + kt)*8 + dt*2 + kk)*512 + (quad*16 + l15)*8 + j]
//     = V^T[d = dt*16+l15][t = kt*64 + (kk*4+quad)*8 + j]
// so an attn V-fragment load is ONE fully-coalesced 1KB global_load_dwordx4.
// ---------------------------------------------------------------------------
__global__ __launch_bounds__(256) void vtrans_kernel(
    const short* __restrict__ qkv, short* __restrict__ vt2) {
  __shared__ __align__(16) short Ts[64 * 80];
  const int kt = blockIdx.x;        // kv-tile (64 rows of t)
  const int t0 = kt * 64;
  const int bh = blockIdx.y;
  const int b = bh >> 4, h = bh & 15;
  const int tid = threadIdx.x;
#pragma unroll
  for (int it = 0; it < 2; ++it) {
    const int ci = tid + it * 256;
    const int t = ci >> 3, cw = ci & 7;
    short8 v = *(const short8*)(qkv + (size_t)(b * 2048 + t0 + t) * 3072 +
                                2048 + h * 64 + cw * 8);
    *(short8*)&Ts[t * 80 + cw * 8] = v;
  }
  __syncthreads();
#pragma unroll
  for (int it = 0; it < 2; ++it) {
    const int ci = tid + it * 256;
    const int d = ci >> 3, c2 = ci & 7;   // d = head dim, c2 = t-chunk
    short tmp[8];
#pragma unroll
    for (int j = 0; j < 8; ++j) tmp[j] = Ts[(c2 * 8 + j) * 80 + d];
    short* dst = vt2 +
        (size_t)((bh * 32 + kt) * 8 + (d >> 4) * 2 + (c2 >> 2)) * 512 +
        ((c2 & 3) * 16 + (d & 15)) * 8;
    *(short8*)dst = *(short8*)tmp;
  }
}

// ---------------------------------------------------------------------------
// Causal flash attention — r11 (resubmit; round-3 run died to an infra
// container failure with no counters, so the experiment is unchanged).
// r9/r10 post-mortem: occupancy 2x (null) and LDS-traffic -43% (null) =>
// the invariant cost is the per-64-kv-tile __syncthreads (full vmcnt/lgkm
// drain + cross-SIMD rendezvous, 33x/block) plus the short serial chain
// between barriers (only 16 MFMA/wave per barrier region).
// Changes vs r10:
//  1. KVBLK=128 per barrier (two 64-kv sub-tiles per staged K tile):
//     17 barriers instead of 33; 2x DMA prefetch window; one long basic
//     block lets sub0's PV (MFMA) overlap sub1's V-loads/K-reads/QK.
//     LDS = 2x16KB K dbuf + 8KB P = 40KB -> still 4 blocks/CU (160KB).
//  2. Deferred l_r reduction: per-lane partials in-loop; the 2 chained
//     shuffles move to the epilogue (x1 instead of x33).
//  3. T5 setprio(1/0) around QK and PV MFMA clusters (+4-7% proven attn).
// V stays r10-style (global fragment-major, L2/LLC-served). K staging,
// P-through-LDS, masking, epilogue unchanged.
// ---------------------------------------------------------------------------
__global__ __launch_bounds__(256, 4) void attn_kernel(
    const short* __restrict__ qkv, const short* __restrict__ vt2,
    short* __restrict__ y) {
  __shared__ __align__(16) short Ks[2][8192];  // [buf][128 rows t][64 d]
  __shared__ __align__(16) short Ps[4][1024];  // per-wave P / epilogue

  const int bh    = blockIdx.x;     // 0..63  (XCD = bh % 8 for all pairi)
  const int pairi = blockIdx.y;     // 0..15
  const int b = bh >> 4, h = bh & 15;
  const int tid  = threadIdx.x;
  const int lane = tid & 63;
  const int wave = tid >> 6;
  const int quad = lane >> 4, l15 = lane & 15;
  const int base_row = b * 2048;
  short* Pw = &Ps[wave][0];

  // K staging: 128 rows x 8 chunks = 1024 slots, 4 per thread.
  // slot s -> row=s>>3, chunk=(s&7)^(row&7); dst shorts s*8
  int srow[4], scol[4];
  const short* kb[4];
#pragma unroll
  for (int it = 0; it < 4; ++it) {
    const int s = tid + it * 256;
    srow[it] = s >> 3;
    scol[it] = ((s & 7) ^ (srow[it] & 7)) * 8;
    kb[it] = qkv + (size_t)(base_row + srow[it]) * 3072 + 1024 + h * 64 + scol[it];
  }

  // V fragment base: per (bh, kt64) an 8KB fragment-major block; this lane's
  // slice starts at lane*8 shorts within each 1KB sub-block.
  const short* v2base = vt2 + (size_t)bh * 32 * 4096 + (size_t)lane * 8;

  const int xk = l15 & 7;  // frag-read chunk XOR

  for (int half = 0; half < 2; ++half) {
    const int qi    = half ? (31 - pairi) : pairi;  // 64-row q-tile index
    const int nkt   = (qi + 2) >> 1;                // 128-row kv tiles
    const int qg0   = qi * 64 + wave * 16;          // this wave's q-group base

    // Q fragments (B-operand): lane holds Q[q=l15][d=quad*8..+7] per half
    short8 qf[2];
    {
      const short* qp = qkv +
          (size_t)(base_row + qg0 + l15) * 3072 + h * 64 + quad * 8;
      qf[0] = *(const short8*)qp;
      qf[1] = *(const short8*)(qp + 32);
    }
    float l_part = 0.f;
    f32x4 o[4];
#pragma unroll
    for (int dt = 0; dt < 4; ++dt) o[dt] = (f32x4){0.f, 0.f, 0.f, 0.f};

    // prologue: stage K 128-tile 0 into buffer 0
#pragma unroll
    for (int it = 0; it < 4; ++it)
      async16(kb[it], &Ks[0][(tid + it * 256) * 8]);

    for (int kt = 0; kt < nkt; ++kt) {
      __syncthreads();  // drains vmcnt -> buf[kt&1] ready; prev reads done

      // prefetch next K 128-tile into the other buffer
      if (kt + 1 < nkt) {
        const size_t koff = (size_t)(kt + 1) * 128 * 3072;
#pragma unroll
        for (int it = 0; it < 4; ++it)
          async16(kb[it] + koff, &Ks[(kt + 1) & 1][(tid + it * 256) * 8]);
      }
      const short* Kb = &Ks[kt & 1][0];

#pragma unroll
      for (int sub = 0; sub < 2; ++sub) {
        const int kvb = kt * 128 + sub * 64;
        if (kvb > qg0 + 15) break;  // fully masked sub-tile (uniform/wave)

        // V frags (A-operand) straight from global, coalesced 1KB each.
        const short* vp = v2base + (size_t)(2 * kt + sub) * 4096;
        short8 vf[4][2];
#pragma unroll
        for (int dt = 0; dt < 4; ++dt) {
          vf[dt][0] = *(const short8*)(vp + (dt * 2 + 0) * 512);
          vf[dt][1] = *(const short8*)(vp + (dt * 2 + 1) * 512);
        }

        // K frags (A-operand): row t=sub*64+nt*16+l15, chunk (kk*4+quad)^xk
        short8 kf[4][2];
#pragma unroll
        for (int nt = 0; nt < 4; ++nt) {
          const int rk = (sub * 64 + nt * 16 + l15) * 64;
          kf[nt][0] = *(const short8*)&Kb[rk + ((quad) ^ xk) * 8];
          kf[nt][1] = *(const short8*)&Kb[rk + ((4 + quad) ^ xk) * 8];
        }

        // S^T = K Q^T : lane gets S^T[kv=nt*16+quad*4+reg][q=l15]
        f32x4 s[4];
        __builtin_amdgcn_s_setprio(1);
#pragma unroll
        for (int nt = 0; nt < 4; ++nt) {
          s[nt] = MFMA_BF16(kf[nt][0], qf[0], ((f32x4){0.f, 0.f, 0.f, 0.f}));
          s[nt] = MFMA_BF16(kf[nt][1], qf[1], s[nt]);
        }
        __builtin_amdgcn_s_setprio(0);

        // p = exp2(s); mask only on the diagonal tile (kvb+64 > qg0)
        float p[4][4];
        if (kvb + 64 <= qg0) {
#pragma unroll
          for (int nt = 0; nt < 4; ++nt)
#pragma unroll
            for (int r = 0; r < 4; ++r)
              p[nt][r] = __builtin_amdgcn_exp2f(s[nt][r]);
        } else {
          const int qrel = qg0 + l15 - kvb;
#pragma unroll
          for (int nt = 0; nt < 4; ++nt)
#pragma unroll
            for (int r = 0; r < 4; ++r) {
              const int kvl = nt * 16 + quad * 4 + r;
              p[nt][r] = (kvl <= qrel) ? __builtin_amdgcn_exp2f(s[nt][r]) : 0.f;
            }
        }

        // per-lane partial row sum (cross-lane reduction deferred to epilogue)
        float rs = ((p[0][0] + p[0][1]) + (p[0][2] + p[0][3])) +
                   ((p[1][0] + p[1][1]) + (p[1][2] + p[1][3])) +
                   ((p[2][0] + p[2][1]) + (p[2][2] + p[2][3])) +
                   ((p[3][0] + p[3][1]) + (p[3][2] + p[3][3]));
        l_part += rs;

        // P -> LDS, layout [f][chunk][q]x16B; pair p0 = 8nt+2quad
#pragma unroll
        for (int nt = 0; nt < 4; ++nt) {
          u32 w0 = pack_bf16_trunc(p[nt][0], p[nt][1]);
          u32 w1 = pack_bf16_trunc(p[nt][2], p[nt][3]);
          const int p0 = 8 * nt + 2 * quad;
          u32* dst = (u32*)Pw + (p0 >> 4) * 256 + ((p0 >> 2) & 3) * 64 +
                     l15 * 4 + (p0 & 3);
          *(uint2*)dst = make_uint2(w0, w1);
        }
        // P frags (B-operand): contiguous b128, conflict-free
        short8 pf0 = *(const short8*)&Pw[quad * 128 + l15 * 8];
        short8 pf1 = *(const short8*)&Pw[512 + quad * 128 + l15 * 8];

        // O^T += V^T P^T : lane gets O^T[d=dt*16+quad*4+reg][q=l15]
        __builtin_amdgcn_s_setprio(1);
#pragma unroll
        for (int dt = 0; dt < 4; ++dt) {
          o[dt] = MFMA_BF16(vf[dt][0], pf0, o[dt]);
          o[dt] = MFMA_BF16(vf[dt][1], pf1, o[dt]);
        }
        __builtin_amdgcn_s_setprio(0);
      }
    }

    // epilogue: finish l_r reduction, normalize, transpose via per-wave LDS
    {
      float l_r = l_part;
      l_r += __shfl_xor(l_r, 16);
      l_r += __shfl_xor(l_r, 32);
      const float inv = 1.f / l_r;
#pragma unroll
      for (int dt = 0; dt < 4; ++dt) {
        const int d = dt * 16 + quad * 4;
        u32 w0 = pack_bf16_trunc(o[dt][0] * inv, o[dt][1] * inv);
        u32 w1 = pack_bf16_trunc(o[dt][2] * inv, o[dt][3] * inv);
        *(uint2*)&Pw[(d >> 5) * 512 + l15 * 32 + (d & 31)] = make_uint2(w0, w1);
      }
      const int qq = lane >> 2, ck = lane & 3;
      const size_t yrow = (size_t)(base_row + qg0 + qq);
#pragma unroll
      for (int kkd = 0; kkd < 2; ++kkd) {
        short8 vv = *(const short8*)&Pw[kkd * 512 + qq * 32 + ck * 8];
        *(short8*)(y + yrow * 1024 + h * 64 + kkd * 32 + ck * 8) = vv;
      }
    }
    __syncthreads();  // all K/P reads of this half done before next prologue
  }
}

// ---------------------------------------------------------------------------
// launch
// ---------------------------------------------------------------------------
extern "C" void kernel_launch(void* const* d_in, const int* in_sizes, int n_in,
                              void* d_out, int out_size, void* d_ws,
                              size_t ws_size, hipStream_t stream) {
  const float* x  = (const float*)d_in[0];   // [4,2048,1024]
  const float* wa = (const float*)d_in[1];   // [3072,1024]
  const float* wp = (const float*)d_in[2];   // [1024,1024]
  float* out = (float*)d_out;                // [4,2048,1024] fp32

  char* ws = (char*)d_ws;
  short* xb  = (short*)(ws + 0);             // 16 MB (reused as vt2 later)
  short* wab = (short*)(ws + 16777216);      // 6 MB
  short* wpb = (short*)(ws + 23068672);      // 2 MB
  short* qkv = (short*)(ws + 25165824);      // 48 MB
  short* yb  = (short*)(ws + 75497472);      // 16 MB
  short* vtb = xb;  // x no longer needed after GEMM1; reuse its 16 MB

  // fused casts (x, wa with q-scale, wp): 3145728 float4 elems
  cast_all_kernel<<<12288, 256, 0, stream>>>(x, wa, wp, xb, wab, wpb);

  // qkv = x @ w_attn^T (q pre-scaled): M=8192 N=3072 K=1024 -> bf16
  gemm_bt_kernel<true><<<dim3(3072 / 128, 8192 / 128), 256, 0, stream>>>(
      xb, wab, (void*)qkv, 8192, 3072, 1024);

  // v-part of qkv -> fragment-major vt2
  vtrans_kernel<<<dim3(32, 64), 256, 0, stream>>>(qkv, vtb);

  // balanced causal flash attention -> y bf16 [8192,1024]
  attn_kernel<<<dim3(64, 16), 256, 0, stream>>>(qkv, vtb, yb);

  // out = y @ w_proj^T : M=8192 N=1024 K=1024 -> fp32
  gemm_bt_kernel<false><<<dim3(1024 / 128, 8192 / 128), 256, 0, stream>>>(
      yb, wpb, (void*)out, 8192, 1024, 1024);
}

// Round 5
// 249.959 us; speedup vs baseline: 1.0278x; 1.0278x over previous
//
#include <hip/hip_runtime.h>
#include <cstdint>
#include <cstddef>

typedef __attribute__((ext_vector_type(8))) short short8;
typedef __attribute__((ext_vector_type(4))) float f32x4;
typedef unsigned int u32;

#define MFMA_BF16(a, b, c) __builtin_amdgcn_mfma_f32_16x16x32_bf16((a), (b), (c), 0, 0, 0)

// ---------------------------------------------------------------------------
// helpers
// ---------------------------------------------------------------------------
__device__ __forceinline__ void async16(const void* g, void* l) {
  __builtin_amdgcn_global_load_lds(
      (const __attribute__((address_space(1))) u32*)g,
      (__attribute__((address_space(3))) u32*)l, 16, 0, 0);
}

__device__ __forceinline__ short f2bf(float f) {
  u32 u = __builtin_bit_cast(u32, f);
  u += 0x7fffu + ((u >> 16) & 1u);  // round-to-nearest-even
  return (short)(u >> 16);
}

// truncating pack: [bf16(lo) | bf16(hi)<<16] in ONE v_perm_b32
__device__ __forceinline__ u32 pack_bf16_trunc(float lo, float hi) {
  return __builtin_amdgcn_perm(__builtin_bit_cast(u32, hi),
                               __builtin_bit_cast(u32, lo), 0x07060302u);
}

// ---------------------------------------------------------------------------
// fused cast fp32 -> bf16 for x, w_attn (q-rows pre-scaled), w_proj
// region sizes (float4 units): x 2097152, wa 786432 (first 262144 scaled), wp 262144
// ---------------------------------------------------------------------------
__global__ __launch_bounds__(256) void cast_all_kernel(
    const float* __restrict__ x, const float* __restrict__ wa,
    const float* __restrict__ wp, short* __restrict__ xb,
    short* __restrict__ wab, short* __restrict__ wpb) {
  const int i = blockIdx.x * blockDim.x + threadIdx.x;
  const float4* src;
  short4* dst;
  float sc = 1.0f;
  if (i < 2097152) {
    src = (const float4*)x + i;
    dst = (short4*)xb + i;
  } else if (i < 2883584) {
    const int j = i - 2097152;
    if (j < 262144) sc = 0.18033688011112042f;  // 1/sqrt(64)*log2(e)
    src = (const float4*)wa + j;
    dst = (short4*)wab + j;
  } else {
    const int j = i - 2883584;
    src = (const float4*)wp + j;
    dst = (short4*)wpb + j;
  }
  float4 v = *src;
  short4 r;
  r.x = f2bf(v.x * sc); r.y = f2bf(v.y * sc);
  r.z = f2bf(v.z * sc); r.w = f2bf(v.w * sc);
  *dst = r;
}

// ---------------------------------------------------------------------------
// C[M][N] = A[M][K] * Bt[N][K]^T   (bf16-as-short in, fp32 accumulate)
// BK=64 — 32 MFMAs + 16 ds_reads per barrier. 128x128 tile,
// single-buffered 32 KB LDS. XCD swizzle (needs gridDim.y==64).
// LDS: 128 B rows, XOR-chunk placement: slot s holds
// T[row=s>>3][chunk=(s&7)^(row&7)]; frag reads at chunk (kk*4+quad)^(l15&7)
// = 2-way bank alias = free (m136).
// ---------------------------------------------------------------------------
template <bool OUT_BF16>
__global__ __launch_bounds__(256) void gemm_bt_kernel(
    const short* __restrict__ A, const short* __restrict__ Bt,
    void* __restrict__ Cv, int M, int N, int K) {
  __shared__ __align__(16) short As[128 * 64];
  __shared__ __align__(16) short Bs[128 * 64];

  const int tid  = threadIdx.x;
  const int lane = tid & 63;
  const int wave = tid >> 6;
  const int quad = lane >> 4;
  const int l15  = lane & 15;

  // XCD swizzle (gridDim.y == 64): linear id -> (bx, by)
  const int id  = blockIdx.y * gridDim.x + blockIdx.x;
  const int xcd = id & 7;
  const int j   = id >> 3;
  const int by  = xcd * 8 + (j & 7);
  const int bx  = j >> 3;
  const int bm  = by * 128;
  const int bn  = bx * 128;

  const int wm = (wave >> 1) * 64;
  const int wn = (wave & 1) * 64;

  f32x4 acc[4][4];
#pragma unroll
  for (int i = 0; i < 4; ++i)
#pragma unroll
    for (int jj = 0; jj < 4; ++jj) acc[i][jj] = (f32x4){0.f, 0.f, 0.f, 0.f};

  // staging: 128 rows x 128 B = 1024 slots/tile, 4 slots/thread/tile.
  int srow[4], scol[4];
#pragma unroll
  for (int it = 0; it < 4; ++it) {
    const int s = tid + it * 256;
    srow[it] = s >> 3;
    scol[it] = ((s & 7) ^ (srow[it] & 7)) * 8;
  }
  const int xk = l15 & 7;  // frag-read chunk XOR

  for (int k0 = 0; k0 < K; k0 += 64) {
    __syncthreads();
#pragma unroll
    for (int it = 0; it < 4; ++it) {
      const int s = tid + it * 256;
      async16(A  + (size_t)(bm + srow[it]) * K + k0 + scol[it], &As[s * 8]);
      async16(Bt + (size_t)(bn + srow[it]) * K + k0 + scol[it], &Bs[s * 8]);
    }
    __syncthreads();

    short8 af[4][2], bf[4][2];
#pragma unroll
    for (int mt = 0; mt < 4; ++mt) {
      const int ra = (wm + mt * 16 + l15) * 64;
      af[mt][0] = *(const short8*)&As[ra + ((quad) ^ xk) * 8];
      af[mt][1] = *(const short8*)&As[ra + ((4 + quad) ^ xk) * 8];
    }
#pragma unroll
    for (int nt = 0; nt < 4; ++nt) {
      const int rb = (wn + nt * 16 + l15) * 64;
      bf[nt][0] = *(const short8*)&Bs[rb + ((quad) ^ xk) * 8];
      bf[nt][1] = *(const short8*)&Bs[rb + ((4 + quad) ^ xk) * 8];
    }
#pragma unroll
    for (int kk = 0; kk < 2; ++kk)
#pragma unroll
      for (int mt = 0; mt < 4; ++mt)
#pragma unroll
        for (int nt = 0; nt < 4; ++nt)
          acc[mt][nt] = MFMA_BF16(af[mt][kk], bf[nt][kk], acc[mt][nt]);
  }

  // epilogue: C/D layout col = lane&15, row = quad*4 + reg
#pragma unroll
  for (int mt = 0; mt < 4; ++mt) {
    const int r0e = bm + wm + mt * 16 + quad * 4;
#pragma unroll
    for (int nt = 0; nt < 4; ++nt) {
      const int c = bn + wn + nt * 16 + l15;
#pragma unroll
      for (int reg = 0; reg < 4; ++reg) {
        float v = acc[mt][nt][reg];
        if (OUT_BF16)
          ((short*)Cv)[(size_t)(r0e + reg) * N + c] = f2bf(v);
        else
          ((float*)Cv)[(size_t)(r0e + reg) * N + c] = v;
      }
    }
  }
}

// ---------------------------------------------------------------------------
// V transpose+repack: qkv v-part [B*T][h*64+d] -> fragment-major vt2:
//   vt2[((bh*32 + kt)*8 + dt*2 + kk)*512 + (quad*16 + l15)*8 + j]
//     = V^T[d = dt*16+l15][t = kt*64 + (kk*4+quad)*8 + j]
// so an attn V-fragment load is ONE fully-coalesced 1KB global_load_dwordx4.
// ---------------------------------------------------------------------------
__global__ __launch_bounds__(256) void vtrans_kernel(
    const short* __restrict__ qkv, short* __restrict__ vt2) {
  __shared__ __align__(16) short Ts[64 * 80];
  const int kt = blockIdx.x;        // kv-tile (64 rows of t)
  const int t0 = kt * 64;
  const int bh = blockIdx.y;
  const int b = bh >> 4, h = bh & 15;
  const int tid = threadIdx.x;
#pragma unroll
  for (int it = 0; it < 2; ++it) {
    const int ci = tid + it * 256;
    const int t = ci >> 3, cw = ci & 7;
    short8 v = *(const short8*)(qkv + (size_t)(b * 2048 + t0 + t) * 3072 +
                                2048 + h * 64 + cw * 8);
    *(short8*)&Ts[t * 80 + cw * 8] = v;
  }
  __syncthreads();
#pragma unroll
  for (int it = 0; it < 2; ++it) {
    const int ci = tid + it * 256;
    const int d = ci >> 3, c2 = ci & 7;   // d = head dim, c2 = t-chunk
    short tmp[8];
#pragma unroll
    for (int j = 0; j < 8; ++j) tmp[j] = Ts[(c2 * 8 + j) * 80 + d];
    short* dst = vt2 +
        (size_t)((bh * 32 + kt) * 8 + (d >> 4) * 2 + (c2 >> 2)) * 512 +
        ((c2 & 3) * 16 + (d & 15)) * 8;
    *(short8*)dst = *(short8*)tmp;
  }
}

// ---------------------------------------------------------------------------
// Causal flash attention — r12: counted-vmcnt pipeline (T4), KVBLK back to 64.
// r11 post-mortem: KVBLK=128 regressed (84us, FETCH/WRITE ~1.8x) — reverted.
// The real structural flaw (r8..r10 invariant): __syncthreads = FULL
// vmcnt(0)+lgkmcnt(0) drain, 33x/block; kt+1 prefetch must complete within
// ONE tile (~1100cy) vs ~900cy loaded-HBM latency => all 4 waves stall
// together at nearly every barrier (the "no pipe >35%" profile). Also r10
// issued prefetch BEFORE the V global loads, so the compiler's pre-PV wait
// was vmcnt(0) — draining the prefetch mid-tile, every tile.
// Fix:
//  - K triple-buffered (3x8KB), DMA prefetch TWO tiles ahead (~2200cy cover).
//  - Barrier = asm s_waitcnt vmcnt(2) [vmcnt(0) on last tiles; wave-uniform]
//    + sched_barrier(0) + raw s_barrier. Never a full drain in the loop.
//    vmcnt in-order-retire semantics (m135) make count=2 exact: at barrier kt
//    the only ops newer than tile-kt's 2 DMAs are tile-(kt+1)'s 2 DMAs.
//  - V loads issued FIRST, then prefetch DMA (sched_barrier pins order), so
//    compiler's pre-PV wait is vmcnt(2) and the prefetch survives the tile.
//  - Cross-wave reuse safety: DMA(kt+2) targets buf[(kt+2)%3] = buf[(kt-1)%3],
//    whose reads completed before waves reached barrier kt (reads feed QK of
//    tile kt-1); DMA is issued after s_barrier => ordered.
// LDS = 24KB K + 8KB P = 32KB. Deferred l_r + setprio kept from r11.
// ---------------------------------------------------------------------------
__global__ __launch_bounds__(256, 4) void attn_kernel(
    const short* __restrict__ qkv, const short* __restrict__ vt2,
    short* __restrict__ y) {
  __shared__ __align__(16) short Ks[3][4096];  // [buf][row t][64 d]
  __shared__ __align__(16) short Ps[4][1024];  // per-wave P / epilogue

  const int bh    = blockIdx.x;     // 0..63  (XCD = bh % 8 for all pairi)
  const int pairi = blockIdx.y;     // 0..15
  const int b = bh >> 4, h = bh & 15;
  const int tid  = threadIdx.x;
  const int lane = tid & 63;
  const int wave = tid >> 6;
  const int quad = lane >> 4, l15 = lane & 15;
  const int base_row = b * 2048;
  short* Pw = &Ps[wave][0];

  // K staging: slot s -> row=s>>3, chunk=(s&7)^(row&7); dst shorts s*8
  const int s0 = tid, s1 = tid + 256;
  const int r0s = s0 >> 3, c0s = (s0 & 7) ^ (r0s & 7);
  const int r1s = s1 >> 3, c1s = (s1 & 7) ^ (r1s & 7);
  const short* kbase0 = qkv + (size_t)(base_row + r0s) * 3072 + 1024 + h * 64 + c0s * 8;
  const short* kbase1 = qkv + (size_t)(base_row + r1s) * 3072 + 1024 + h * 64 + c1s * 8;

  // V fragment base: per (bh, kt) an 8KB fragment-major block; this lane's
  // slice starts at lane*8 shorts within each 1KB sub-block.
  const short* v2base = vt2 + (size_t)bh * 32 * 4096 + (size_t)lane * 8;

  const int xk = l15 & 7;  // frag-read chunk XOR

  for (int half = 0; half < 2; ++half) {
    const int qi  = half ? (31 - pairi) : pairi;  // 64-row q-tile index
    const int nkt = qi + 1;                       // kv tiles 0..qi
    const int qg0 = qi * 64 + wave * 16;          // this wave's q-group base

    // Q fragments (B-operand): lane holds Q[q=l15][d=quad*8..+7] per half
    short8 qf[2];
    {
      const short* qp = qkv +
          (size_t)(base_row + qg0 + l15) * 3072 + h * 64 + quad * 8;
      qf[0] = *(const short8*)qp;
      qf[1] = *(const short8*)(qp + 32);
    }
    float l_part = 0.f;
    f32x4 o[4];
#pragma unroll
    for (int dt = 0; dt < 4; ++dt) o[dt] = (f32x4){0.f, 0.f, 0.f, 0.f};

    // prologue: stage K tiles 0 (and 1) into buffers 0 (and 1)
    async16(kbase0, &Ks[0][s0 * 8]);
    async16(kbase1, &Ks[0][s1 * 8]);
    if (nkt > 1) {
      async16(kbase0 + (size_t)64 * 3072, &Ks[1][s0 * 8]);
      async16(kbase1 + (size_t)64 * 3072, &Ks[1][s1 * 8]);
    }

    int cb = 0;  // buffer index = kt % 3
    for (int kt = 0; kt < nkt; ++kt) {
      const int kvb = kt * 64;

      // wait: tile-kt's 2 DMAs done. In-flight beyond them: only tile-(kt+1)'s
      // 2 DMAs (if issued). Wave-uniform branch (nkt uniform per block).
      if (kt + 1 < nkt) {
        asm volatile("s_waitcnt vmcnt(2)" ::: "memory");
      } else {
        asm volatile("s_waitcnt vmcnt(0)" ::: "memory");
      }
      __builtin_amdgcn_sched_barrier(0);
      __builtin_amdgcn_s_barrier();  // all waves: buf[cb] ready, old reads done

      // V frags (A-operand) straight from global, coalesced 1KB each.
      // Issued BEFORE the prefetch DMA so the compiler's pre-PV wait is
      // vmcnt(2), not vmcnt(0).
      const short* vp = v2base + (size_t)kt * 4096;
      short8 vf[4][2];
#pragma unroll
      for (int dt = 0; dt < 4; ++dt) {
        vf[dt][0] = *(const short8*)(vp + (dt * 2 + 0) * 512);
        vf[dt][1] = *(const short8*)(vp + (dt * 2 + 1) * 512);
      }
      __builtin_amdgcn_sched_barrier(0);  // pin: V loads above, DMA below

      // prefetch K tile kt+2 into buf[(kt+2)%3] (the one tile kt-1 used)
      if (kt + 2 < nkt) {
        int pb = cb + 2; if (pb >= 3) pb -= 3;
        const size_t koff = (size_t)(kvb + 128) * 3072;
        async16(kbase0 + koff, &Ks[pb][s0 * 8]);
        async16(kbase1 + koff, &Ks[pb][s1 * 8]);
      }
      const short* Kb = &Ks[cb][0];

      // K frags (A-operand): row t=nt*16+l15, chunk (kk*4+quad)^xk
      short8 kf[4][2];
#pragma unroll
      for (int nt = 0; nt < 4; ++nt) {
        kf[nt][0] = *(const short8*)&Kb[(nt * 16 + l15) * 64 + ((quad) ^ xk) * 8];
        kf[nt][1] = *(const short8*)&Kb[(nt * 16 + l15) * 64 + ((4 + quad) ^ xk) * 8];
      }

      // S^T = K Q^T : lane gets S^T[kv=nt*16+quad*4+reg][q=l15]
      f32x4 s[4];
      __builtin_amdgcn_s_setprio(1);
#pragma unroll
      for (int nt = 0; nt < 4; ++nt) {
        s[nt] = MFMA_BF16(kf[nt][0], qf[0], ((f32x4){0.f, 0.f, 0.f, 0.f}));
        s[nt] = MFMA_BF16(kf[nt][1], qf[1], s[nt]);
      }
      __builtin_amdgcn_s_setprio(0);

      // p = exp2(s); mask only on the diagonal tile (kvb+64 > qg0)
      float p[4][4];
      if (kvb + 64 <= qg0) {
#pragma unroll
        for (int nt = 0; nt < 4; ++nt)
#pragma unroll
          for (int r = 0; r < 4; ++r)
            p[nt][r] = __builtin_amdgcn_exp2f(s[nt][r]);
      } else {
        const int qrel = qg0 + l15 - kvb;
#pragma unroll
        for (int nt = 0; nt < 4; ++nt)
#pragma unroll
          for (int r = 0; r < 4; ++r) {
            const int kvl = nt * 16 + quad * 4 + r;
            p[nt][r] = (kvl <= qrel) ? __builtin_amdgcn_exp2f(s[nt][r]) : 0.f;
          }
      }

      // per-lane partial row sum (cross-lane reduction deferred to epilogue)
      float rs = ((p[0][0] + p[0][1]) + (p[0][2] + p[0][3])) +
                 ((p[1][0] + p[1][1]) + (p[1][2] + p[1][3])) +
                 ((p[2][0] + p[2][1]) + (p[2][2] + p[2][3])) +
                 ((p[3][0] + p[3][1]) + (p[3][2] + p[3][3]));
      l_part += rs;

      // P -> LDS, layout [f][chunk][q]x16B; pair p0 = 8nt+2quad
#pragma unroll
      for (int nt = 0; nt < 4; ++nt) {
        u32 w0 = pack_bf16_trunc(p[nt][0], p[nt][1]);
        u32 w1 = pack_bf16_trunc(p[nt][2], p[nt][3]);
        const int p0 = 8 * nt + 2 * quad;
        u32* dst = (u32*)Pw + (p0 >> 4) * 256 + ((p0 >> 2) & 3) * 64 +
                   l15 * 4 + (p0 & 3);
        *(uint2*)dst = make_uint2(w0, w1);
      }
      // P frags (B-operand): contiguous b128, conflict-free (per-wave LDS,
      // compiler-managed lgkmcnt)
      short8 pf0 = *(const short8*)&Pw[quad * 128 + l15 * 8];
      short8 pf1 = *(const short8*)&Pw[512 + quad * 128 + l15 * 8];

      // O^T += V^T P^T : lane gets O^T[d=dt*16+quad*4+reg][q=l15]
      __builtin_amdgcn_s_setprio(1);
#pragma unroll
      for (int dt = 0; dt < 4; ++dt) {
        o[dt] = MFMA_BF16(vf[dt][0], pf0, o[dt]);
        o[dt] = MFMA_BF16(vf[dt][1], pf1, o[dt]);
      }
      __builtin_amdgcn_s_setprio(0);

      cb = (cb == 2) ? 0 : cb + 1;
    }

    // epilogue: finish l_r reduction, normalize, transpose via per-wave LDS
    {
      float l_r = l_part;
      l_r += __shfl_xor(l_r, 16);
      l_r += __shfl_xor(l_r, 32);
      const float inv = 1.f / l_r;
#pragma unroll
      for (int dt = 0; dt < 4; ++dt) {
        const int d = dt * 16 + quad * 4;
        u32 w0 = pack_bf16_trunc(o[dt][0] * inv, o[dt][1] * inv);
        u32 w1 = pack_bf16_trunc(o[dt][2] * inv, o[dt][3] * inv);
        *(uint2*)&Pw[(d >> 5) * 512 + l15 * 32 + (d & 31)] = make_uint2(w0, w1);
      }
      const int qq = lane >> 2, ck = lane & 3;
      const size_t yrow = (size_t)(base_row + qg0 + qq);
#pragma unroll
      for (int kkd = 0; kkd < 2; ++kkd) {
        short8 vv = *(const short8*)&Pw[kkd * 512 + qq * 32 + ck * 8];
        *(short8*)(y + yrow * 1024 + h * 64 + kkd * 32 + ck * 8) = vv;
      }
    }
    __syncthreads();  // full drain: all K/P reads + stores done before next half
  }
}

// ---------------------------------------------------------------------------
// launch
// ---------------------------------------------------------------------------
extern "C" void kernel_launch(void* const* d_in, const int* in_sizes, int n_in,
                              void* d_out, int out_size, void* d_ws,
                              size_t ws_size, hipStream_t stream) {
  const float* x  = (const float*)d_in[0];   // [4,2048,1024]
  const float* wa = (const float*)d_in[1];   // [3072,1024]
  const float* wp = (const float*)d_in[2];   // [1024,1024]
  float* out = (float*)d_out;                // [4,2048,1024] fp32

  char* ws = (char*)d_ws;
  short* xb  = (short*)(ws + 0);             // 16 MB (reused as vt2 later)
  short* wab = (short*)(ws + 16777216);      // 6 MB
  short* wpb = (short*)(ws + 23068672);      // 2 MB
  short* qkv = (short*)(ws + 25165824);      // 48 MB
  short* yb  = (short*)(ws + 75497472);      // 16 MB
  short* vtb = xb;  // x no longer needed after GEMM1; reuse its 16 MB

  // fused casts (x, wa with q-scale, wp): 3145728 float4 elems
  cast_all_kernel<<<12288, 256, 0, stream>>>(x, wa, wp, xb, wab, wpb);

  // qkv = x @ w_attn^T (q pre-scaled): M=8192 N=3072 K=1024 -> bf16
  gemm_bt_kernel<true><<<dim3(3072 / 128, 8192 / 128), 256, 0, stream>>>(
      xb, wab, (void*)qkv, 8192, 3072, 1024);

  // v-part of qkv -> fragment-major vt2
  vtrans_kernel<<<dim3(32, 64), 256, 0, stream>>>(qkv, vtb);

  // balanced causal flash attention -> y bf16 [8192,1024]
  attn_kernel<<<dim3(64, 16), 256, 0, stream>>>(qkv, vtb, yb);

  // out = y @ w_proj^T : M=8192 N=1024 K=1024 -> fp32
  gemm_bt_kernel<false><<<dim3(1024 / 128, 8192 / 128), 256, 0, stream>>>(
      yb, wpb, (void*)out, 8192, 1024, 1024);
}

// Round 6
// 242.727 us; speedup vs baseline: 1.0585x; 1.0298x over previous
//
#include <hip/hip_runtime.h>
#include <cstdint>
#include <cstddef>

typedef __attribute__((ext_vector_type(8))) short short8;
typedef __attribute__((ext_vector_type(4))) float f32x4;
typedef unsigned int u32;

#define MFMA_BF16(a, b, c) __builtin_amdgcn_mfma_f32_16x16x32_bf16((a), (b), (c), 0, 0, 0)

// ---------------------------------------------------------------------------
// helpers
// ---------------------------------------------------------------------------
__device__ __forceinline__ void async16(const void* g, void* l) {
  __builtin_amdgcn_global_load_lds(
      (const __attribute__((address_space(1))) u32*)g,
      (__attribute__((address_space(3))) u32*)l, 16, 0, 0);
}

__device__ __forceinline__ short f2bf(float f) {
  u32 u = __builtin_bit_cast(u32, f);
  u += 0x7fffu + ((u >> 16) & 1u);  // round-to-nearest-even
  return (short)(u >> 16);
}

// truncating pack: [bf16(lo) | bf16(hi)<<16] in ONE v_perm_b32
__device__ __forceinline__ u32 pack_bf16_trunc(float lo, float hi) {
  return __builtin_amdgcn_perm(__builtin_bit_cast(u32, hi),
                               __builtin_bit_cast(u32, lo), 0x07060302u);
}

// ---------------------------------------------------------------------------
// fused cast fp32 -> bf16 for x, w_attn (q-rows pre-scaled), w_proj
// region sizes (float4 units): x 2097152, wa 786432 (first 262144 scaled), wp 262144
// ---------------------------------------------------------------------------
__global__ __launch_bounds__(256) void cast_all_kernel(
    const float* __restrict__ x, const float* __restrict__ wa,
    const float* __restrict__ wp, short* __restrict__ xb,
    short* __restrict__ wab, short* __restrict__ wpb) {
  const int i = blockIdx.x * blockDim.x + threadIdx.x;
  const float4* src;
  short4* dst;
  float sc = 1.0f;
  if (i < 2097152) {
    src = (const float4*)x + i;
    dst = (short4*)xb + i;
  } else if (i < 2883584) {
    const int j = i - 2097152;
    if (j < 262144) sc = 0.18033688011112042f;  // 1/sqrt(64)*log2(e)
    src = (const float4*)wa + j;
    dst = (short4*)wab + j;
  } else {
    const int j = i - 2883584;
    src = (const float4*)wp + j;
    dst = (short4*)wpb + j;
  }
  float4 v = *src;
  short4 r;
  r.x = f2bf(v.x * sc); r.y = f2bf(v.y * sc);
  r.z = f2bf(v.z * sc); r.w = f2bf(v.w * sc);
  *dst = r;
}

// ---------------------------------------------------------------------------
// C[M][N] = A[M][K] * Bt[N][K]^T   (bf16-as-short in, fp32 accumulate)
// BK=64 — 32 MFMAs + 16 ds_reads per barrier. 128x128 tile,
// single-buffered 32 KB LDS. XCD swizzle (needs gridDim.y==64).
// LDS: 128 B rows, XOR-chunk placement: slot s holds
// T[row=s>>3][chunk=(s&7)^(row&7)]; frag reads at chunk (kk*4+quad)^(l15&7)
// = 2-way bank alias = free (m136).
// ---------------------------------------------------------------------------
template <bool OUT_BF16>
__global__ __launch_bounds__(256) void gemm_bt_kernel(
    const short* __restrict__ A, const short* __restrict__ Bt,
    void* __restrict__ Cv, int M, int N, int K) {
  __shared__ __align__(16) short As[128 * 64];
  __shared__ __align__(16) short Bs[128 * 64];

  const int tid  = threadIdx.x;
  const int lane = tid & 63;
  const int wave = tid >> 6;
  const int quad = lane >> 4;
  const int l15  = lane & 15;

  // XCD swizzle (gridDim.y == 64): linear id -> (bx, by)
  const int id  = blockIdx.y * gridDim.x + blockIdx.x;
  const int xcd = id & 7;
  const int j   = id >> 3;
  const int by  = xcd * 8 + (j & 7);
  const int bx  = j >> 3;
  const int bm  = by * 128;
  const int bn  = bx * 128;

  const int wm = (wave >> 1) * 64;
  const int wn = (wave & 1) * 64;

  f32x4 acc[4][4];
#pragma unroll
  for (int i = 0; i < 4; ++i)
#pragma unroll
    for (int jj = 0; jj < 4; ++jj) acc[i][jj] = (f32x4){0.f, 0.f, 0.f, 0.f};

  // staging: 128 rows x 128 B = 1024 slots/tile, 4 slots/thread/tile.
  int srow[4], scol[4];
#pragma unroll
  for (int it = 0; it < 4; ++it) {
    const int s = tid + it * 256;
    srow[it] = s >> 3;
    scol[it] = ((s & 7) ^ (srow[it] & 7)) * 8;
  }
  const int xk = l15 & 7;  // frag-read chunk XOR

  for (int k0 = 0; k0 < K; k0 += 64) {
    __syncthreads();
#pragma unroll
    for (int it = 0; it < 4; ++it) {
      const int s = tid + it * 256;
      async16(A  + (size_t)(bm + srow[it]) * K + k0 + scol[it], &As[s * 8]);
      async16(Bt + (size_t)(bn + srow[it]) * K + k0 + scol[it], &Bs[s * 8]);
    }
    __syncthreads();

    short8 af[4][2], bf[4][2];
#pragma unroll
    for (int mt = 0; mt < 4; ++mt) {
      const int ra = (wm + mt * 16 + l15) * 64;
      af[mt][0] = *(const short8*)&As[ra + ((quad) ^ xk) * 8];
      af[mt][1] = *(const short8*)&As[ra + ((4 + quad) ^ xk) * 8];
    }
#pragma unroll
    for (int nt = 0; nt < 4; ++nt) {
      const int rb = (wn + nt * 16 + l15) * 64;
      bf[nt][0] = *(const short8*)&Bs[rb + ((quad) ^ xk) * 8];
      bf[nt][1] = *(const short8*)&Bs[rb + ((4 + quad) ^ xk) * 8];
    }
#pragma unroll
    for (int kk = 0; kk < 2; ++kk)
#pragma unroll
      for (int mt = 0; mt < 4; ++mt)
#pragma unroll
        for (int nt = 0; nt < 4; ++nt)
          acc[mt][nt] = MFMA_BF16(af[mt][kk], bf[nt][kk], acc[mt][nt]);
  }

  // epilogue: C/D layout col = lane&15, row = quad*4 + reg
#pragma unroll
  for (int mt = 0; mt < 4; ++mt) {
    const int r0e = bm + wm + mt * 16 + quad * 4;
#pragma unroll
    for (int nt = 0; nt < 4; ++nt) {
      const int c = bn + wn + nt * 16 + l15;
#pragma unroll
      for (int reg = 0; reg < 4; ++reg) {
        float v = acc[mt][nt][reg];
        if (OUT_BF16)
          ((short*)Cv)[(size_t)(r0e + reg) * N + c] = f2bf(v);
        else
          ((float*)Cv)[(size_t)(r0e + reg) * N + c] = v;
      }
    }
  }
}

// ---------------------------------------------------------------------------
// V transpose+repack: qkv v-part [B*T][h*64+d] -> fragment-major vt2:
//   vt2[((bh*32 + kt)*8 + dt*2 + kk)*512 + (quad*16 + l15)*8 + j]
//     = V^T[d = dt*16+l15][t = kt*64 + (kk*4+quad)*8 + j]
// so an attn V-fragment load is ONE fully-coalesced 1KB global_load_dwordx4.
// ---------------------------------------------------------------------------
__global__ __launch_bounds__(256) void vtrans_kernel(
    const short* __restrict__ qkv, short* __restrict__ vt2) {
  __shared__ __align__(16) short Ts[64 * 80];
  const int kt = blockIdx.x;        // kv-tile (64 rows of t)
  const int t0 = kt * 64;
  const int bh = blockIdx.y;
  const int b = bh >> 4, h = bh & 15;
  const int tid = threadIdx.x;
#pragma unroll
  for (int it = 0; it < 2; ++it) {
    const int ci = tid + it * 256;
    const int t = ci >> 3, cw = ci & 7;
    short8 v = *(const short8*)(qkv + (size_t)(b * 2048 + t0 + t) * 3072 +
                                2048 + h * 64 + cw * 8);
    *(short8*)&Ts[t * 80 + cw * 8] = v;
  }
  __syncthreads();
#pragma unroll
  for (int it = 0; it < 2; ++it) {
    const int ci = tid + it * 256;
    const int d = ci >> 3, c2 = ci & 7;   // d = head dim, c2 = t-chunk
    short tmp[8];
#pragma unroll
    for (int j = 0; j < 8; ++j) tmp[j] = Ts[(c2 * 8 + j) * 80 + d];
    short* dst = vt2 +
        (size_t)((bh * 32 + kt) * 8 + (d >> 4) * 2 + (c2 >> 2)) * 512 +
        ((c2 & 3) * 16 + (d & 15)) * 8;
    *(short8*)dst = *(short8*)tmp;
  }
}

// ---------------------------------------------------------------------------
// Causal flash attention — r13: force V fragments live (the VGPR=64 theory).
// Six-experiment post-mortem (r9..r12): occupancy 2x null, LDS -43% null,
// barrier /2 mem-regression, counted-vmcnt pipeline null. The overlooked
// counter: VGPR_Count=64 while live-set needs ~110 (vf 32 + kf 32 + o 16 +
// qf 8 + s/p 32). The register allocator SERIALIZED the tile: V loads sunk
// to right before PV (sched_barrier can't stop regalloc sinking), ~600-900cy
// loaded-latency stall mid-chain every tile -> all pipes <35%, per-tile
// ~5K cyc, immune to occupancy/LDS/barrier changes.
// Fix: V loads as inline-asm global_load_dwordx4 with "=v" outputs issued
// right after the tile barrier (volatile asm cannot sink; forces ~32 extra
// live VGPRs), counted s_waitcnt vmcnt(2) just before PV (V's 8 loads
// retired; kt+2 K-DMAs stay in flight — in-order retire), sched_barrier(0)
// after the wait (rule #18: block MFMA hoist). Budget: __launch_bounds__
// (256,4) allows 128 VGPR; expected allocation ~100-128, still 4 blocks/CU.
// Everything else identical to r12 (3-buf K DMA 2-ahead, counted barrier
// waits, deferred l_r, setprio, P-through-LDS).
// ---------------------------------------------------------------------------
__global__ __launch_bounds__(256, 4) void attn_kernel(
    const short* __restrict__ qkv, const short* __restrict__ vt2,
    short* __restrict__ y) {
  __shared__ __align__(16) short Ks[3][4096];  // [buf][row t][64 d]
  __shared__ __align__(16) short Ps[4][1024];  // per-wave P / epilogue

  const int bh    = blockIdx.x;     // 0..63  (XCD = bh % 8 for all pairi)
  const int pairi = blockIdx.y;     // 0..15
  const int b = bh >> 4, h = bh & 15;
  const int tid  = threadIdx.x;
  const int lane = tid & 63;
  const int wave = tid >> 6;
  const int quad = lane >> 4, l15 = lane & 15;
  const int base_row = b * 2048;
  short* Pw = &Ps[wave][0];

  // K staging: slot s -> row=s>>3, chunk=(s&7)^(row&7); dst shorts s*8
  const int s0 = tid, s1 = tid + 256;
  const int r0s = s0 >> 3, c0s = (s0 & 7) ^ (r0s & 7);
  const int r1s = s1 >> 3, c1s = (s1 & 7) ^ (r1s & 7);
  const short* kbase0 = qkv + (size_t)(base_row + r0s) * 3072 + 1024 + h * 64 + c0s * 8;
  const short* kbase1 = qkv + (size_t)(base_row + r1s) * 3072 + 1024 + h * 64 + c1s * 8;

  // V fragment base: per (bh, kt) an 8KB fragment-major block; this lane's
  // slice starts at lane*8 shorts within each 1KB sub-block.
  const short* v2base = vt2 + (size_t)bh * 32 * 4096 + (size_t)lane * 8;

  const int xk = l15 & 7;  // frag-read chunk XOR

  for (int half = 0; half < 2; ++half) {
    const int qi  = half ? (31 - pairi) : pairi;  // 64-row q-tile index
    const int nkt = qi + 1;                       // kv tiles 0..qi
    const int qg0 = qi * 64 + wave * 16;          // this wave's q-group base

    // Q fragments (B-operand): lane holds Q[q=l15][d=quad*8..+7] per half
    short8 qf[2];
    {
      const short* qp = qkv +
          (size_t)(base_row + qg0 + l15) * 3072 + h * 64 + quad * 8;
      qf[0] = *(const short8*)qp;
      qf[1] = *(const short8*)(qp + 32);
    }
    float l_part = 0.f;
    f32x4 o[4];
#pragma unroll
    for (int dt = 0; dt < 4; ++dt) o[dt] = (f32x4){0.f, 0.f, 0.f, 0.f};

    // prologue: stage K tiles 0 (and 1) into buffers 0 (and 1)
    async16(kbase0, &Ks[0][s0 * 8]);
    async16(kbase1, &Ks[0][s1 * 8]);
    if (nkt > 1) {
      async16(kbase0 + (size_t)64 * 3072, &Ks[1][s0 * 8]);
      async16(kbase1 + (size_t)64 * 3072, &Ks[1][s1 * 8]);
    }

    int cb = 0;  // buffer index = kt % 3
    for (int kt = 0; kt < nkt; ++kt) {
      const int kvb = kt * 64;

      // tile-top wait: tile-kt's K-DMAs done. In-order retire: V(kt-1)
      // retired at the pre-PV wait of tile kt-1, and DMA(kt) preceded them,
      // so vmcnt(2) (= allow DMA(kt+1) in flight) is exact.
      if (kt + 1 < nkt) {
        asm volatile("s_waitcnt vmcnt(2)" ::: "memory");
      } else {
        asm volatile("s_waitcnt vmcnt(0)" ::: "memory");
      }
      __builtin_amdgcn_sched_barrier(0);
      __builtin_amdgcn_s_barrier();  // all waves: buf[cb] ready, old reads done

      // V frags (A-operand): inline-asm loads, pinned HERE. 8x coalesced 1KB.
      // "=v" outputs force ~32 VGPRs live across QK+softmax -> regalloc
      // cannot sink these under PV. Latency hides under K-reads+QK+softmax.
      const short* vp0 = v2base + (size_t)kt * 4096;
      const short* vp1 = vp0 + 2048;
      short8 vf[4][2];
      asm volatile("global_load_dwordx4 %0, %1, off"             : "=v"(vf[0][0]) : "v"(vp0));
      asm volatile("global_load_dwordx4 %0, %1, off offset:1024" : "=v"(vf[0][1]) : "v"(vp0));
      asm volatile("global_load_dwordx4 %0, %1, off offset:2048" : "=v"(vf[1][0]) : "v"(vp0));
      asm volatile("global_load_dwordx4 %0, %1, off offset:3072" : "=v"(vf[1][1]) : "v"(vp0));
      asm volatile("global_load_dwordx4 %0, %1, off"             : "=v"(vf[2][0]) : "v"(vp1));
      asm volatile("global_load_dwordx4 %0, %1, off offset:1024" : "=v"(vf[2][1]) : "v"(vp1));
      asm volatile("global_load_dwordx4 %0, %1, off offset:2048" : "=v"(vf[3][0]) : "v"(vp1));
      asm volatile("global_load_dwordx4 %0, %1, off offset:3072" : "=v"(vf[3][1]) : "v"(vp1));
      __builtin_amdgcn_sched_barrier(0);  // pin: V loads above, DMA below

      // prefetch K tile kt+2 into buf[(kt+2)%3] (the one tile kt-1 used)
      if (kt + 2 < nkt) {
        int pb = cb + 2; if (pb >= 3) pb -= 3;
        const size_t koff = (size_t)(kvb + 128) * 3072;
        async16(kbase0 + koff, &Ks[pb][s0 * 8]);
        async16(kbase1 + koff, &Ks[pb][s1 * 8]);
      }
      const short* Kb = &Ks[cb][0];

      // K frags (A-operand): row t=nt*16+l15, chunk (kk*4+quad)^xk
      short8 kf[4][2];
#pragma unroll
      for (int nt = 0; nt < 4; ++nt) {
        kf[nt][0] = *(const short8*)&Kb[(nt * 16 + l15) * 64 + ((quad) ^ xk) * 8];
        kf[nt][1] = *(const short8*)&Kb[(nt * 16 + l15) * 64 + ((4 + quad) ^ xk) * 8];
      }

      // S^T = K Q^T : lane gets S^T[kv=nt*16+quad*4+reg][q=l15]
      f32x4 s[4];
      __builtin_amdgcn_s_setprio(1);
#pragma unroll
      for (int nt = 0; nt < 4; ++nt) {
        s[nt] = MFMA_BF16(kf[nt][0], qf[0], ((f32x4){0.f, 0.f, 0.f, 0.f}));
        s[nt] = MFMA_BF16(kf[nt][1], qf[1], s[nt]);
      }
      __builtin_amdgcn_s_setprio(0);

      // p = exp2(s); mask only on the diagonal tile (kvb+64 > qg0)
      float p[4][4];
      if (kvb + 64 <= qg0) {
#pragma unroll
        for (int nt = 0; nt < 4; ++nt)
#pragma unroll
          for (int r = 0; r < 4; ++r)
            p[nt][r] = __builtin_amdgcn_exp2f(s[nt][r]);
      } else {
        const int qrel = qg0 + l15 - kvb;
#pragma unroll
        for (int nt = 0; nt < 4; ++nt)
#pragma unroll
          for (int r = 0; r < 4; ++r) {
            const int kvl = nt * 16 + quad * 4 + r;
            p[nt][r] = (kvl <= qrel) ? __builtin_amdgcn_exp2f(s[nt][r]) : 0.f;
          }
      }

      // per-lane partial row sum (cross-lane reduction deferred to epilogue)
      float rs = ((p[0][0] + p[0][1]) + (p[0][2] + p[0][3])) +
                 ((p[1][0] + p[1][1]) + (p[1][2] + p[1][3])) +
                 ((p[2][0] + p[2][1]) + (p[2][2] + p[2][3])) +
                 ((p[3][0] + p[3][1]) + (p[3][2] + p[3][3]));
      l_part += rs;

      // P -> LDS, layout [f][chunk][q]x16B; pair p0 = 8nt+2quad
#pragma unroll
      for (int nt = 0; nt < 4; ++nt) {
        u32 w0 = pack_bf16_trunc(p[nt][0], p[nt][1]);
        u32 w1 = pack_bf16_trunc(p[nt][2], p[nt][3]);
        const int p0 = 8 * nt + 2 * quad;
        u32* dst = (u32*)Pw + (p0 >> 4) * 256 + ((p0 >> 2) & 3) * 64 +
                   l15 * 4 + (p0 & 3);
        *(uint2*)dst = make_uint2(w0, w1);
      }
      // P frags (B-operand): contiguous b128, conflict-free (per-wave LDS,
      // compiler-managed lgkmcnt)
      short8 pf0 = *(const short8*)&Pw[quad * 128 + l15 * 8];
      short8 pf1 = *(const short8*)&Pw[512 + quad * 128 + l15 * 8];

      // pre-PV wait: V's 8 asm loads retired; DMA(kt+2) (if issued) stays
      // in flight. sched_barrier blocks PV-MFMA hoist above the wait.
      if (kt + 2 < nkt) {
        asm volatile("s_waitcnt vmcnt(2)" ::: "memory");
      } else {
        asm volatile("s_waitcnt vmcnt(0)" ::: "memory");
      }
      __builtin_amdgcn_sched_barrier(0);

      // O^T += V^T P^T : lane gets O^T[d=dt*16+quad*4+reg][q=l15]
      __builtin_amdgcn_s_setprio(1);
#pragma unroll
      for (int dt = 0; dt < 4; ++dt) {
        o[dt] = MFMA_BF16(vf[dt][0], pf0, o[dt]);
        o[dt] = MFMA_BF16(vf[dt][1], pf1, o[dt]);
      }
      __builtin_amdgcn_s_setprio(0);

      cb = (cb == 2) ? 0 : cb + 1;
    }

    // epilogue: finish l_r reduction, normalize, transpose via per-wave LDS
    {
      float l_r = l_part;
      l_r += __shfl_xor(l_r, 16);
      l_r += __shfl_xor(l_r, 32);
      const float inv = 1.f / l_r;
#pragma unroll
      for (int dt = 0; dt < 4; ++dt) {
        const int d = dt * 16 + quad * 4;
        u32 w0 = pack_bf16_trunc(o[dt][0] * inv, o[dt][1] * inv);
        u32 w1 = pack_bf16_trunc(o[dt][2] * inv, o[dt][3] * inv);
        *(uint2*)&Pw[(d >> 5) * 512 + l15 * 32 + (d & 31)] = make_uint2(w0, w1);
      }
      const int qq = lane >> 2, ck = lane & 3;
      const size_t yrow = (size_t)(base_row + qg0 + qq);
#pragma unroll
      for (int kkd = 0; kkd < 2; ++kkd) {
        short8 vv = *(const short8*)&Pw[kkd * 512 + qq * 32 + ck * 8];
        *(short8*)(y + yrow * 1024 + h * 64 + kkd * 32 + ck * 8) = vv;
      }
    }
    __syncthreads();  // full drain: all K/P reads + stores done before next half
  }
}

// ---------------------------------------------------------------------------
// launch
// ---------------------------------------------------------------------------
extern "C" void kernel_launch(void* const* d_in, const int* in_sizes, int n_in,
                              void* d_out, int out_size, void* d_ws,
                              size_t ws_size, hipStream_t stream) {
  const float* x  = (const float*)d_in[0];   // [4,2048,1024]
  const float* wa = (const float*)d_in[1];   // [3072,1024]
  const float* wp = (const float*)d_in[2];   // [1024,1024]
  float* out = (float*)d_out;                // [4,2048,1024] fp32

  char* ws = (char*)d_ws;
  short* xb  = (short*)(ws + 0);             // 16 MB (reused as vt2 later)
  short* wab = (short*)(ws + 16777216);      // 6 MB
  short* wpb = (short*)(ws + 23068672);      // 2 MB
  short* qkv = (short*)(ws + 25165824);      // 48 MB
  short* yb  = (short*)(ws + 75497472);      // 16 MB
  short* vtb = xb;  // x no longer needed after GEMM1; reuse its 16 MB

  // fused casts (x, wa with q-scale, wp): 3145728 float4 elems
  cast_all_kernel<<<12288, 256, 0, stream>>>(x, wa, wp, xb, wab, wpb);

  // qkv = x @ w_attn^T (q pre-scaled): M=8192 N=3072 K=1024 -> bf16
  gemm_bt_kernel<true><<<dim3(3072 / 128, 8192 / 128), 256, 0, stream>>>(
      xb, wab, (void*)qkv, 8192, 3072, 1024);

  // v-part of qkv -> fragment-major vt2
  vtrans_kernel<<<dim3(32, 64), 256, 0, stream>>>(qkv, vtb);

  // balanced causal flash attention -> y bf16 [8192,1024]
  attn_kernel<<<dim3(64, 16), 256, 0, stream>>>(qkv, vtb, yb);

  // out = y @ w_proj^T : M=8192 N=1024 K=1024 -> fp32
  gemm_bt_kernel<false><<<dim3(1024 / 128, 8192 / 128), 256, 0, stream>>>(
      yb, wpb, (void*)out, 8192, 1024, 1024);
}